// Round 1
// baseline (205.375 us; speedup 1.0000x reference)
//
#include <hip/hip_runtime.h>
#include <hip/hip_bf16.h>

#define D_MODEL 1024
#define D_HEAD  64
#define T_SEQ   4096
#define NB      4
#define NROWS   (NB * T_SEQ)      // 16384
#define SPLIT   8

typedef float f32x4 __attribute__((ext_vector_type(4)));
typedef __bf16 bf16x8 __attribute__((ext_vector_type(8)));
typedef unsigned short u16;

__device__ inline unsigned pk_bf16(float a, float b) {
    unsigned ua = __builtin_bit_cast(unsigned, a);
    unsigned ub = __builtin_bit_cast(unsigned, b);
    ua = (ua + 0x7FFFu + ((ua >> 16) & 1u)) >> 16;   // RNE
    ub = (ub + 0x7FFFu + ((ub >> 16) & 1u)) >> 16;
    return ua | (ub << 16);
}
__device__ inline u16 bf16r(float a) {
    unsigned ua = __builtin_bit_cast(unsigned, a);
    return (u16)((ua + 0x7FFFu + ((ua >> 16) & 1u)) >> 16);
}

// ---------------- W pre-pack: Wpk[kb][n][j] = W_sel[(kb*8+j)*64 + col], bf16 ----------------
__global__ __launch_bounds__(256) void packw_kernel(
    const float* __restrict__ Wq, const float* __restrict__ Wk,
    const float* __restrict__ Wv, unsigned* __restrict__ Wpk)
{
    const int id = blockIdx.x * 256 + threadIdx.x;   // 0..24575
    const int kb = id / 192;
    const int n  = id - kb * 192;
    const int sel = n >> 6, col = n & 63;
    const float* W = sel == 0 ? Wq : (sel == 1 ? Wk : Wv);
    float f[8];
#pragma unroll
    for (int j = 0; j < 8; ++j) f[j] = W[(kb * 8 + j) * 64 + col];
    uint4 o;
    o.x = pk_bf16(f[0], f[1]); o.y = pk_bf16(f[2], f[3]);
    o.z = pk_bf16(f[4], f[5]); o.w = pk_bf16(f[6], f[7]);
    *(uint4*)(Wpk + (size_t)id * 4) = o;
}

// ---------------- QKV projection: streaming LDS-staged GEMM, BK=128 dbuf (R11) --------------
__global__ __launch_bounds__(256) void qkv_kernel(
    const float* __restrict__ x, const unsigned* __restrict__ Wpk,
    u16* __restrict__ Qbf, u16* __restrict__ Kbf, u16* __restrict__ Vt)
{
    __shared__ __align__(16) unsigned Xs[2][32 * 68];   // 32 rows x 128 bf16 (stride 136)
    __shared__ __align__(16) u16 Vbuf[64 * 32];         // V^T bounce: [dim 64][tpos 32]

    const int tid  = threadIdx.x;
    const int w    = tid >> 6;
    const int lane = tid & 63;
    const int nl   = lane & 15;
    const int quad = lane >> 4;
    const long row0 = (long)blockIdx.x * 32;

    const int srow = tid >> 5;          // staging: base row 0..7 (+8 per pass)
    const int scol = (tid & 31) * 4;    // staging col 0..124

    f32x4 acc[2][3] = {};

    float4 nx[4];
#pragma unroll
    for (int p = 0; p < 4; ++p)
        nx[p] = *(const float4*)(x + (row0 + p * 8 + srow) * D_MODEL + scol);

    for (int ch = 0; ch < 8; ++ch) {
        const int buf = ch & 1;
#pragma unroll
        for (int p = 0; p < 4; ++p) {
            uint2 pk2;
            pk2.x = pk_bf16(nx[p].x, nx[p].y);
            pk2.y = pk_bf16(nx[p].z, nx[p].w);
            *(uint2*)&Xs[buf][(p * 8 + srow) * 68 + (scol >> 1)] = pk2;
        }
        __syncthreads();
        if (ch < 7) {
#pragma unroll
            for (int p = 0; p < 4; ++p)
                nx[p] = *(const float4*)(x + (row0 + p * 8 + srow) * D_MODEL
                                           + (ch + 1) * 128 + scol);
        }
#pragma unroll
        for (int kk = 0; kk < 4; ++kk) {
            const bf16x8 a0 = __builtin_bit_cast(bf16x8,
                *(const uint4*)&Xs[buf][nl * 68 + kk * 16 + quad * 4]);
            const bf16x8 a1 = __builtin_bit_cast(bf16x8,
                *(const uint4*)&Xs[buf][(16 + nl) * 68 + kk * 16 + quad * 4]);
            const unsigned* wb = Wpk + (size_t)(ch * 16 + kk * 4 + quad) * 768
                                     + (w * 48 + nl) * 4;
#pragma unroll
            for (int t = 0; t < 3; ++t) {
                const bf16x8 b = __builtin_bit_cast(bf16x8, *(const uint4*)(wb + t * 64));
                acc[0][t] = __builtin_amdgcn_mfma_f32_16x16x32_bf16(a0, b, acc[0][t], 0, 0, 0);
                acc[1][t] = __builtin_amdgcn_mfma_f32_16x16x32_bf16(a1, b, acc[1][t], 0, 0, 0);
            }
        }
        __syncthreads();
    }

    const float QSCALE = 0.04508422f;    // D^-0.5 * log2(e): exp2-domain prescale
#pragma unroll
    for (int t = 0; t < 3; ++t) {
        const int n0c = w * 48 + t * 16;
        const int sel = n0c >> 6;
        const int col = (n0c & 63) + nl;
#pragma unroll
        for (int m = 0; m < 2; ++m) {
            if (sel == 0) {
#pragma unroll
                for (int reg = 0; reg < 4; ++reg)
                    Qbf[(row0 + m * 16 + quad * 4 + reg) * D_HEAD + col] =
                        bf16r(acc[m][t][reg] * QSCALE);
            } else if (sel == 1) {
#pragma unroll
                for (int reg = 0; reg < 4; ++reg)
                    Kbf[(row0 + m * 16 + quad * 4 + reg) * D_HEAD + col] =
                        bf16r(acc[m][t][reg]);
            } else {
                uint2 p2;
                p2.x = pk_bf16(acc[m][t][0], acc[m][t][1]);
                p2.y = pk_bf16(acc[m][t][2], acc[m][t][3]);
                *(uint2*)&Vbuf[col * 32 + m * 16 + quad * 4] = p2;
            }
        }
    }
    __syncthreads();
    {
        const int dim  = tid >> 2;
        const int tseg = (tid & 3) * 8;
        const long bb   = row0 >> 12;
        const int tpos0 = (int)(row0 & 4095);
        const uint4 v = *(const uint4*)&Vbuf[dim * 32 + tseg];
        *(uint4*)&Vt[((bb * 64 + dim) << 12) + tpos0 + tseg] = v;
    }
}

// ---------------- MFMA flash attention: 32 q-rows per wave (2 strips), K-split 8 ------------
// R12: each wave processes a 32-row Q tile (strips 2*tile, 2*tile+1) per 64-row K/V tile,
// halving L2-sourced K/V traffic vs 16-row strips (latency/concurrency-bound regime).
// Single dispatch; blockIdx%8 XCD round-robin pins each XCD to one batch (K+V = 4MB = L2).
// Po16/Pl layout identical to R10 (strip = tile*2+m) so reduce_kernel is unchanged.
__global__ __launch_bounds__(256, 4) void attn_kernel(
    const u16* __restrict__ Qbf, const u16* __restrict__ Kbf,
    const u16* __restrict__ Vt, u16* __restrict__ Po16, float* __restrict__ Pl)
{
    __shared__ __align__(16) u16 Pbuf[4][2][16 * 64];   // 16 KB

    const int tid   = threadIdx.x;
    const int w     = tid >> 6;
    const int lane  = tid & 63;
    const int nl    = lane & 15;
    const int quad  = lane >> 4;
    const int gid   = blockIdx.x;
    const int b     = gid & 3;
    const int idx   = gid >> 2;                  // 0..255
    const int tile  = 127 - (idx >> 1);          // long tiles dispatched first
    const int sp    = (idx & 1) * 4 + w;         // global split 0..7
    const int wq0   = tile * 32;

    const u16* Kb = Kbf + (size_t)b * T_SEQ * D_HEAD;
    const u16* Vb = Vt  + (size_t)b * D_HEAD * T_SEQ;

    bf16x8 qf[2][2];
#pragma unroll
    for (int m = 0; m < 2; ++m) {
        const u16* qp = Qbf + ((size_t)b * T_SEQ + wq0 + m * 16 + nl) * D_HEAD + quad * 8;
        qf[m][0] = __builtin_bit_cast(bf16x8, *(const uint4*)qp);
        qf[m][1] = __builtin_bit_cast(bf16x8, *(const uint4*)(qp + 32));
    }

    f32x4 Ot[2][4] = {};
    float l[2][4] = {{0.f,0.f,0.f,0.f},{0.f,0.f,0.f,0.f}};
    // both strips of the tile share one tile count (wq0+15 and wq0+31 are in the same
    // 64-row K-tile for every 32-aligned wq0); m=0's extra coverage is fully masked.
    const int nt = (wq0 + 95) >> 6;

    uint4 vfr[4][2];

    for (int kt = sp; kt < nt; kt += SPLIT) {
        const int k0 = kt << 6;

        uint4 kfr[4][2];
#pragma unroll
        for (int t = 0; t < 4; ++t) {
            const u16* kp = Kb + (size_t)(k0 + t * 16 + nl) * D_HEAD + quad * 8;
            kfr[t][0] = *(const uint4*)kp;
            kfr[t][1] = *(const uint4*)(kp + 32);
        }

#pragma unroll
        for (int m = 0; m < 2; ++m) {
            f32x4 S[4];
#pragma unroll
            for (int t = 0; t < 4; ++t) {
                f32x4 z = {};
                z = __builtin_amdgcn_mfma_f32_16x16x32_bf16(qf[m][0],
                        __builtin_bit_cast(bf16x8, kfr[t][0]), z, 0, 0, 0);
                S[t] = __builtin_amdgcn_mfma_f32_16x16x32_bf16(qf[m][1],
                        __builtin_bit_cast(bf16x8, kfr[t][1]), z, 0, 0, 0);
            }

            // issue V loads after the last use of kfr (m==1 QK^T); their latency hides
            // under m=1's exp2/pack/LDS work, and kfr regs are dead -> peak VGPR <= ~128
            if (m == 1) {
#pragma unroll
                for (int t = 0; t < 4; ++t) {
                    const u16* vp = Vb + (size_t)(t * 16 + nl) * T_SEQ + k0 + quad * 8;
                    vfr[t][0] = *(const uint4*)vp;
                    vfr[t][1] = *(const uint4*)(vp + 32);
                }
            }

            const int qb = wq0 + m * 16;
            if (k0 + 63 > qb) {
#pragma unroll
                for (int t = 0; t < 4; ++t)
#pragma unroll
                    for (int reg = 0; reg < 4; ++reg)
                        if (k0 + t * 16 + nl > qb + quad * 4 + reg) S[t][reg] = -INFINITY;
            }

#pragma unroll
            for (int t = 0; t < 4; ++t)
#pragma unroll
                for (int reg = 0; reg < 4; ++reg)
                    S[t][reg] = exp2f(S[t][reg]);
#pragma unroll
            for (int reg = 0; reg < 4; ++reg)
                l[m][reg] += (S[0][reg] + S[1][reg]) + (S[2][reg] + S[3][reg]);

            u16* pb = Pbuf[w][m];
#pragma unroll
            for (int t = 0; t < 4; ++t) {
                const int g = 2 * t + (nl >> 3);
#pragma unroll
                for (int reg = 0; reg < 4; ++reg) {
                    const int q = quad * 4 + reg;
                    pb[q * 64 + ((g ^ (q & 7)) * 8) + (nl & 7)] = bf16r(S[t][reg]);
                }
            }
        }

#pragma unroll
        for (int m = 0; m < 2; ++m) {
            const u16* pb = Pbuf[w][m];
            const bf16x8 pf0 = __builtin_bit_cast(bf16x8,
                *(const uint4*)&pb[nl * 64 + ((quad ^ (nl & 7)) * 8)]);
            const bf16x8 pf1 = __builtin_bit_cast(bf16x8,
                *(const uint4*)&pb[nl * 64 + (((4 + quad) ^ (nl & 7)) * 8)]);
#pragma unroll
            for (int t = 0; t < 4; ++t) {
                Ot[m][t] = __builtin_amdgcn_mfma_f32_16x16x32_bf16(pf0,
                            __builtin_bit_cast(bf16x8, vfr[t][0]), Ot[m][t], 0, 0, 0);
                Ot[m][t] = __builtin_amdgcn_mfma_f32_16x16x32_bf16(pf1,
                            __builtin_bit_cast(bf16x8, vfr[t][1]), Ot[m][t], 0, 0, 0);
            }
        }
    }

#pragma unroll
    for (int m = 0; m < 2; ++m) {
#pragma unroll
        for (int reg = 0; reg < 4; ++reg) {
            float s = l[m][reg];
            s += __shfl_xor(s, 1);
            s += __shfl_xor(s, 2);
            s += __shfl_xor(s, 4);
            s += __shfl_xor(s, 8);
            l[m][reg] = s;
        }
        const int strip = tile * 2 + m;
        const int bs = b * 256 + strip;
        u16* po = Po16 + ((size_t)sp * 1024 + bs) * 1024;
#pragma unroll
        for (int t = 0; t < 4; ++t) {
            uint2 p2;
            p2.x = pk_bf16(Ot[m][t][0], Ot[m][t][1]);
            p2.y = pk_bf16(Ot[m][t][2], Ot[m][t][3]);
            *(uint2*)&po[(t * 16 + nl) * 16 + quad * 4] = p2;
        }
        if (nl == 0) {
            const size_t gr = (size_t)b * T_SEQ + wq0 + m * 16;
#pragma unroll
            for (int reg = 0; reg < 4; ++reg)
                Pl[(size_t)sp * NROWS + gr + quad * 4 + reg] = l[m][reg];
        }
    }
}

// ---------------- merge K-split partials: O[row][col] = sum_sp Po / sum_sp Pl (R10) ---------
__global__ __launch_bounds__(64) void reduce_kernel(
    const u16* __restrict__ Po16, const float* __restrict__ Pl,
    float* __restrict__ O)
{
    __shared__ float linv[16];
    const int bs    = blockIdx.x;
    const int b     = bs >> 8, strip = bs & 255;
    const size_t gr = (size_t)b * T_SEQ + strip * 16;
    const int c     = threadIdx.x;               // col 0..63

    if (c < 16) {
        float s = 0.f;
#pragma unroll
        for (int sp = 0; sp < SPLIT; ++sp) s += Pl[(size_t)sp * NROWS + gr + c];
        linv[c] = 1.0f / s;
    }
    __syncthreads();

    float v[16] = {};
#pragma unroll
    for (int sp = 0; sp < SPLIT; ++sp) {
        const u16* p = Po16 + ((size_t)sp * 1024 + bs) * 1024 + c * 16;
        const uint4 x0 = *(const uint4*)p;
        const uint4 x1 = *(const uint4*)(p + 8);
        const unsigned uu[8] = {x0.x, x0.y, x0.z, x0.w, x1.x, x1.y, x1.z, x1.w};
#pragma unroll
        for (int i = 0; i < 8; ++i) {
            v[2*i]   += __builtin_bit_cast(float, uu[i] << 16);
            v[2*i+1] += __builtin_bit_cast(float, uu[i] & 0xFFFF0000u);
        }
    }
#pragma unroll
    for (int r = 0; r < 16; ++r)
        O[(gr + r) * D_HEAD + c] = v[r] * linv[r];
}

extern "C" void kernel_launch(void* const* d_in, const int* in_sizes, int n_in,
                              void* d_out, int out_size, void* d_ws, size_t ws_size,
                              hipStream_t stream) {
    const float* x  = (const float*)d_in[0];
    const float* Wq = (const float*)d_in[1];
    const float* Wk = (const float*)d_in[2];
    const float* Wv = (const float*)d_in[3];
    float* out = (float*)d_out;

    const size_t rows = NROWS;                        // 16384
    u16* Qbf = (u16*)d_ws;                            // 2 MB
    u16* Kbf = Qbf + rows * D_HEAD;                   // 2 MB
    u16* Vt  = Kbf + rows * D_HEAD;                   // 2 MB (per-batch transposed [b][h][t])
    unsigned* Wpk = (unsigned*)(Vt + rows * D_HEAD);  // 384 KB
    u16* Po16 = (u16*)(Wpk + 128 * 192 * 4);          // SPLIT*16384*64 bf16 = 16 MB
    float* Pl = (float*)(Po16 + (size_t)SPLIT * rows * D_HEAD);  // 512 KB

    hipLaunchKernelGGL(packw_kernel, dim3(96), dim3(256), 0, stream,
                       Wq, Wk, Wv, Wpk);
    hipLaunchKernelGGL(qkv_kernel, dim3(rows / 32), dim3(256), 0, stream,
                       x, Wpk, Qbf, Kbf, Vt);
    hipLaunchKernelGGL(attn_kernel, dim3(NB * 256), dim3(256), 0, stream,
                       Qbf, Kbf, Vt, Po16, Pl);
    hipLaunchKernelGGL(reduce_kernel, dim3(NB * 256), dim3(64), 0, stream,
                       Po16, Pl, out);
}

// Round 2
// 187.239 us; speedup vs baseline: 1.0969x; 1.0969x over previous
//
#include <hip/hip_runtime.h>
#include <hip/hip_bf16.h>

#define D_MODEL 1024
#define D_HEAD  64
#define T_SEQ   4096
#define NB      4
#define NROWS   (NB * T_SEQ)      // 16384
#define SPLIT   8

typedef float f32x4 __attribute__((ext_vector_type(4)));
typedef __bf16 bf16x8 __attribute__((ext_vector_type(8)));
typedef unsigned short u16;

__device__ inline unsigned pk_bf16(float a, float b) {
    unsigned ua = __builtin_bit_cast(unsigned, a);
    unsigned ub = __builtin_bit_cast(unsigned, b);
    ua = (ua + 0x7FFFu + ((ua >> 16) & 1u)) >> 16;   // RNE
    ub = (ub + 0x7FFFu + ((ub >> 16) & 1u)) >> 16;
    return ua | (ub << 16);
}
__device__ inline u16 bf16r(float a) {
    unsigned ua = __builtin_bit_cast(unsigned, a);
    return (u16)((ua + 0x7FFFu + ((ua >> 16) & 1u)) >> 16);
}

// ---------------- W pre-pack: Wpk[kb][n][j] = W_sel[(kb*8+j)*64 + col], bf16 ----------------
__global__ __launch_bounds__(256) void packw_kernel(
    const float* __restrict__ Wq, const float* __restrict__ Wk,
    const float* __restrict__ Wv, unsigned* __restrict__ Wpk)
{
    const int id = blockIdx.x * 256 + threadIdx.x;   // 0..24575
    const int kb = id / 192;
    const int n  = id - kb * 192;
    const int sel = n >> 6, col = n & 63;
    const float* W = sel == 0 ? Wq : (sel == 1 ? Wk : Wv);
    float f[8];
#pragma unroll
    for (int j = 0; j < 8; ++j) f[j] = W[(kb * 8 + j) * 64 + col];
    uint4 o;
    o.x = pk_bf16(f[0], f[1]); o.y = pk_bf16(f[2], f[3]);
    o.z = pk_bf16(f[4], f[5]); o.w = pk_bf16(f[6], f[7]);
    *(uint4*)(Wpk + (size_t)id * 4) = o;
}

// ---------------- QKV projection: streaming LDS-staged GEMM, BK=128 dbuf (R11) --------------
__global__ __launch_bounds__(256) void qkv_kernel(
    const float* __restrict__ x, const unsigned* __restrict__ Wpk,
    u16* __restrict__ Qbf, u16* __restrict__ Kbf, u16* __restrict__ Vt)
{
    __shared__ __align__(16) unsigned Xs[2][32 * 68];   // 32 rows x 128 bf16 (stride 136)
    __shared__ __align__(16) u16 Vbuf[64 * 32];         // V^T bounce: [dim 64][tpos 32]

    const int tid  = threadIdx.x;
    const int w    = tid >> 6;
    const int lane = tid & 63;
    const int nl   = lane & 15;
    const int quad = lane >> 4;
    const long row0 = (long)blockIdx.x * 32;

    const int srow = tid >> 5;          // staging: base row 0..7 (+8 per pass)
    const int scol = (tid & 31) * 4;    // staging col 0..124

    f32x4 acc[2][3] = {};

    float4 nx[4];
#pragma unroll
    for (int p = 0; p < 4; ++p)
        nx[p] = *(const float4*)(x + (row0 + p * 8 + srow) * D_MODEL + scol);

    for (int ch = 0; ch < 8; ++ch) {
        const int buf = ch & 1;
#pragma unroll
        for (int p = 0; p < 4; ++p) {
            uint2 pk2;
            pk2.x = pk_bf16(nx[p].x, nx[p].y);
            pk2.y = pk_bf16(nx[p].z, nx[p].w);
            *(uint2*)&Xs[buf][(p * 8 + srow) * 68 + (scol >> 1)] = pk2;
        }
        __syncthreads();
        if (ch < 7) {
#pragma unroll
            for (int p = 0; p < 4; ++p)
                nx[p] = *(const float4*)(x + (row0 + p * 8 + srow) * D_MODEL
                                           + (ch + 1) * 128 + scol);
        }
#pragma unroll
        for (int kk = 0; kk < 4; ++kk) {
            const bf16x8 a0 = __builtin_bit_cast(bf16x8,
                *(const uint4*)&Xs[buf][nl * 68 + kk * 16 + quad * 4]);
            const bf16x8 a1 = __builtin_bit_cast(bf16x8,
                *(const uint4*)&Xs[buf][(16 + nl) * 68 + kk * 16 + quad * 4]);
            const unsigned* wb = Wpk + (size_t)(ch * 16 + kk * 4 + quad) * 768
                                     + (w * 48 + nl) * 4;
#pragma unroll
            for (int t = 0; t < 3; ++t) {
                const bf16x8 b = __builtin_bit_cast(bf16x8, *(const uint4*)(wb + t * 64));
                acc[0][t] = __builtin_amdgcn_mfma_f32_16x16x32_bf16(a0, b, acc[0][t], 0, 0, 0);
                acc[1][t] = __builtin_amdgcn_mfma_f32_16x16x32_bf16(a1, b, acc[1][t], 0, 0, 0);
            }
        }
        __syncthreads();
    }

    const float QSCALE = 0.04508422f;    // D^-0.5 * log2(e): exp2-domain prescale
#pragma unroll
    for (int t = 0; t < 3; ++t) {
        const int n0c = w * 48 + t * 16;
        const int sel = n0c >> 6;
        const int col = (n0c & 63) + nl;
#pragma unroll
        for (int m = 0; m < 2; ++m) {
            if (sel == 0) {
#pragma unroll
                for (int reg = 0; reg < 4; ++reg)
                    Qbf[(row0 + m * 16 + quad * 4 + reg) * D_HEAD + col] =
                        bf16r(acc[m][t][reg] * QSCALE);
            } else if (sel == 1) {
#pragma unroll
                for (int reg = 0; reg < 4; ++reg)
                    Kbf[(row0 + m * 16 + quad * 4 + reg) * D_HEAD + col] =
                        bf16r(acc[m][t][reg]);
            } else {
                uint2 p2;
                p2.x = pk_bf16(acc[m][t][0], acc[m][t][1]);
                p2.y = pk_bf16(acc[m][t][2], acc[m][t][3]);
                *(uint2*)&Vbuf[col * 32 + m * 16 + quad * 4] = p2;
            }
        }
    }
    __syncthreads();
    {
        const int dim  = tid >> 2;
        const int tseg = (tid & 3) * 8;
        const long bb   = row0 >> 12;
        const int tpos0 = (int)(row0 & 4095);
        const uint4 v = *(const uint4*)&Vbuf[dim * 32 + tseg];
        *(uint4*)&Vt[((bb * 64 + dim) << 12) + tpos0 + tseg] = v;
    }
}

// ---------------- MFMA flash attention: R13 -------------------------------------------------
// R13 changes vs R12 (theory: latency-bound via VGPR-starved load serialization + tail):
//  (a) __launch_bounds__(256,2): ~256-reg budget so all 24 dwordx4 K/V loads of an
//      iteration issue as ONE batch (one vmcnt wait), not ~2-load chunks at 64 VGPRs.
//  (b) explicit 1-deep double-buffered prefetch (named bufs kA/vA/kB/vB, static indexing).
//  (c) balanced grid: tiles (127-p, p) paired -> every pair needs exactly 65 K-tiles.
//      512 blocks (= 2 blocks/CU, all resident), each wave runs its K-split share of
//      tile A then tile B. No diagonal tail. gid&3 keeps one batch per XCD (gid%8 RR).
// Po16/Pl layout identical to R10/R12 (strip = tile*2+m), reduce_kernel unchanged;
// waves with zero items for a tile still write zero partials (reduce sums all 8 sp).
__global__ __launch_bounds__(256, 2) void attn_kernel(
    const u16* __restrict__ Qbf, const u16* __restrict__ Kbf,
    const u16* __restrict__ Vt, u16* __restrict__ Po16, float* __restrict__ Pl)
{
    __shared__ __align__(16) u16 Pbuf[4][2][16 * 64];   // 16 KB

    const int tid   = threadIdx.x;
    const int w     = tid >> 6;
    const int lane  = tid & 63;
    const int nl    = lane & 15;
    const int quad  = lane >> 4;
    const int gid   = blockIdx.x;                // 0..511
    const int b     = gid & 3;                   // one batch per XCD (gid%8 round-robin)
    const int idx   = gid >> 2;                  // 0..127
    const int half  = idx & 1;
    const int pair  = idx >> 1;                  // 0..63
    const int sp    = half * 4 + w;              // global split 0..7

    const u16* Kb = Kbf + (size_t)b * T_SEQ * D_HEAD;
    const u16* Vb = Vt  + (size_t)b * D_HEAD * T_SEQ;

    const int tileA = 127 - pair;
    const int tileB = pair;
    const int nA = (tileA * 32 + 95) >> 6;       // 33..64
    const int nB = (tileB * 32 + 95) >> 6;       // nA + nB == 65 for all pairs
    const int cntA = (nA - sp + 7) >> 3;         // sp < 8 <= nA always
    const int ktB0 = sp + 8 * cntA - nA;         // in [0,8)
    const int cntB = (ktB0 < nB) ? ((nB - ktB0 + 7) >> 3) : 0;

#define LOADKV(kt, kf, vf) do {                                                         \
    const int _k0 = (kt) << 6;                                                          \
    _Pragma("unroll") for (int t = 0; t < 4; ++t) {                                     \
        const u16* kp = Kb + (size_t)(_k0 + t * 16 + nl) * D_HEAD + quad * 8;           \
        kf[t][0] = *(const uint4*)kp;                                                   \
        kf[t][1] = *(const uint4*)(kp + 32);                                            \
    }                                                                                   \
    _Pragma("unroll") for (int t = 0; t < 4; ++t) {                                     \
        const u16* vp = Vb + (size_t)(t * 16 + nl) * T_SEQ + _k0 + quad * 8;            \
        vf[t][0] = *(const uint4*)vp;                                                   \
        vf[t][1] = *(const uint4*)(vp + 32);                                            \
    }                                                                                   \
} while (0)

#define COMPUTEKV(kt, kf, vf) do {                                                      \
    const int _k0 = (kt) << 6;                                                          \
    _Pragma("unroll") for (int m = 0; m < 2; ++m) {                                     \
        f32x4 S[4];                                                                     \
        _Pragma("unroll") for (int t = 0; t < 4; ++t) {                                 \
            f32x4 z = {};                                                               \
            z = __builtin_amdgcn_mfma_f32_16x16x32_bf16(qf[m][0],                       \
                    __builtin_bit_cast(bf16x8, kf[t][0]), z, 0, 0, 0);                  \
            S[t] = __builtin_amdgcn_mfma_f32_16x16x32_bf16(qf[m][1],                    \
                    __builtin_bit_cast(bf16x8, kf[t][1]), z, 0, 0, 0);                  \
        }                                                                               \
        const int _qb = wq0 + m * 16;                                                   \
        if (_k0 + 63 > _qb) {                                                           \
            _Pragma("unroll") for (int t = 0; t < 4; ++t)                               \
            _Pragma("unroll") for (int reg = 0; reg < 4; ++reg)                         \
                if (_k0 + t * 16 + nl > _qb + quad * 4 + reg) S[t][reg] = -INFINITY;    \
        }                                                                               \
        _Pragma("unroll") for (int t = 0; t < 4; ++t)                                   \
        _Pragma("unroll") for (int reg = 0; reg < 4; ++reg)                             \
            S[t][reg] = exp2f(S[t][reg]);                                               \
        _Pragma("unroll") for (int reg = 0; reg < 4; ++reg)                             \
            l[m][reg] += (S[0][reg] + S[1][reg]) + (S[2][reg] + S[3][reg]);             \
        u16* pb = Pbuf[w][m];                                                           \
        _Pragma("unroll") for (int t = 0; t < 4; ++t) {                                 \
            const int g = 2 * t + (nl >> 3);                                            \
            _Pragma("unroll") for (int reg = 0; reg < 4; ++reg) {                       \
                const int q = quad * 4 + reg;                                           \
                pb[q * 64 + ((g ^ (q & 7)) * 8) + (nl & 7)] = bf16r(S[t][reg]);         \
            }                                                                           \
        }                                                                               \
        const bf16x8 pf0 = __builtin_bit_cast(bf16x8,                                   \
            *(const uint4*)&pb[nl * 64 + ((quad ^ (nl & 7)) * 8)]);                     \
        const bf16x8 pf1 = __builtin_bit_cast(bf16x8,                                   \
            *(const uint4*)&pb[nl * 64 + (((4 + quad) ^ (nl & 7)) * 8)]);               \
        _Pragma("unroll") for (int t = 0; t < 4; ++t) {                                 \
            Ot[m][t] = __builtin_amdgcn_mfma_f32_16x16x32_bf16(pf0,                     \
                        __builtin_bit_cast(bf16x8, vf[t][0]), Ot[m][t], 0, 0, 0);       \
            Ot[m][t] = __builtin_amdgcn_mfma_f32_16x16x32_bf16(pf1,                     \
                        __builtin_bit_cast(bf16x8, vf[t][1]), Ot[m][t], 0, 0, 0);       \
        }                                                                               \
    }                                                                                   \
} while (0)

    auto runTile = [&](const int tile, const int kt0, const int cnt) {
        const int wq0 = tile * 32;

        bf16x8 qf[2][2];
#pragma unroll
        for (int m = 0; m < 2; ++m) {
            const u16* qp = Qbf + ((size_t)b * T_SEQ + wq0 + m * 16 + nl) * D_HEAD + quad * 8;
            qf[m][0] = __builtin_bit_cast(bf16x8, *(const uint4*)qp);
            qf[m][1] = __builtin_bit_cast(bf16x8, *(const uint4*)(qp + 32));
        }

        f32x4 Ot[2][4] = {};
        float l[2][4] = {{0.f,0.f,0.f,0.f},{0.f,0.f,0.f,0.f}};

        uint4 kA[4][2], vA[4][2], kB[4][2], vB[4][2];
        int kt = kt0, rem = cnt;
        if (rem > 0) LOADKV(kt, kA, vA);
        while (rem >= 2) {
            LOADKV(kt + 8, kB, vB);          // prefetch next under current compute
            COMPUTEKV(kt, kA, vA);
            if (rem >= 3) LOADKV(kt + 16, kA, vA);
            COMPUTEKV(kt + 8, kB, vB);
            kt += 16; rem -= 2;
        }
        if (rem == 1) COMPUTEKV(kt, kA, vA);

#pragma unroll
        for (int m = 0; m < 2; ++m) {
#pragma unroll
            for (int reg = 0; reg < 4; ++reg) {
                float s = l[m][reg];
                s += __shfl_xor(s, 1);
                s += __shfl_xor(s, 2);
                s += __shfl_xor(s, 4);
                s += __shfl_xor(s, 8);
                l[m][reg] = s;
            }
            const int strip = tile * 2 + m;
            const int bs = b * 256 + strip;
            u16* po = Po16 + ((size_t)sp * 1024 + bs) * 1024;
#pragma unroll
            for (int t = 0; t < 4; ++t) {
                uint2 p2;
                p2.x = pk_bf16(Ot[m][t][0], Ot[m][t][1]);
                p2.y = pk_bf16(Ot[m][t][2], Ot[m][t][3]);
                *(uint2*)&po[(t * 16 + nl) * 16 + quad * 4] = p2;
            }
            if (nl == 0) {
                const size_t gr = (size_t)b * T_SEQ + wq0 + m * 16;
#pragma unroll
                for (int reg = 0; reg < 4; ++reg)
                    Pl[(size_t)sp * NROWS + gr + quad * 4 + reg] = l[m][reg];
            }
        }
    };

    runTile(tileA, sp,   cntA);
    runTile(tileB, ktB0, cntB);

#undef LOADKV
#undef COMPUTEKV
}

// ---------------- merge K-split partials: O[row][col] = sum_sp Po / sum_sp Pl (R10) ---------
__global__ __launch_bounds__(64) void reduce_kernel(
    const u16* __restrict__ Po16, const float* __restrict__ Pl,
    float* __restrict__ O)
{
    __shared__ float linv[16];
    const int bs    = blockIdx.x;
    const int b     = bs >> 8, strip = bs & 255;
    const size_t gr = (size_t)b * T_SEQ + strip * 16;
    const int c     = threadIdx.x;               // col 0..63

    if (c < 16) {
        float s = 0.f;
#pragma unroll
        for (int sp = 0; sp < SPLIT; ++sp) s += Pl[(size_t)sp * NROWS + gr + c];
        linv[c] = 1.0f / s;
    }
    __syncthreads();

    float v[16] = {};
#pragma unroll
    for (int sp = 0; sp < SPLIT; ++sp) {
        const u16* p = Po16 + ((size_t)sp * 1024 + bs) * 1024 + c * 16;
        const uint4 x0 = *(const uint4*)p;
        const uint4 x1 = *(const uint4*)(p + 8);
        const unsigned uu[8] = {x0.x, x0.y, x0.z, x0.w, x1.x, x1.y, x1.z, x1.w};
#pragma unroll
        for (int i = 0; i < 8; ++i) {
            v[2*i]   += __builtin_bit_cast(float, uu[i] << 16);
            v[2*i+1] += __builtin_bit_cast(float, uu[i] & 0xFFFF0000u);
        }
    }
#pragma unroll
    for (int r = 0; r < 16; ++r)
        O[(gr + r) * D_HEAD + c] = v[r] * linv[r];
}

extern "C" void kernel_launch(void* const* d_in, const int* in_sizes, int n_in,
                              void* d_out, int out_size, void* d_ws, size_t ws_size,
                              hipStream_t stream) {
    const float* x  = (const float*)d_in[0];
    const float* Wq = (const float*)d_in[1];
    const float* Wk = (const float*)d_in[2];
    const float* Wv = (const float*)d_in[3];
    float* out = (float*)d_out;

    const size_t rows = NROWS;                        // 16384
    u16* Qbf = (u16*)d_ws;                            // 2 MB
    u16* Kbf = Qbf + rows * D_HEAD;                   // 2 MB
    u16* Vt  = Kbf + rows * D_HEAD;                   // 2 MB (per-batch transposed [b][h][t])
    unsigned* Wpk = (unsigned*)(Vt + rows * D_HEAD);  // 384 KB
    u16* Po16 = (u16*)(Wpk + 128 * 192 * 4);          // SPLIT*16384*64 bf16 = 16 MB
    float* Pl = (float*)(Po16 + (size_t)SPLIT * rows * D_HEAD);  // 512 KB

    hipLaunchKernelGGL(packw_kernel, dim3(96), dim3(256), 0, stream,
                       Wq, Wk, Wv, Wpk);
    hipLaunchKernelGGL(qkv_kernel, dim3(rows / 32), dim3(256), 0, stream,
                       x, Wpk, Qbf, Kbf, Vt);
    hipLaunchKernelGGL(attn_kernel, dim3(512), dim3(256), 0, stream,
                       Qbf, Kbf, Vt, Po16, Pl);
    hipLaunchKernelGGL(reduce_kernel, dim3(NB * 256), dim3(64), 0, stream,
                       Po16, Pl, out);
}

// Round 3
// 155.515 us; speedup vs baseline: 1.3206x; 1.2040x over previous
//
#include <hip/hip_runtime.h>
#include <hip/hip_bf16.h>

#define D_MODEL 1024
#define D_HEAD  64
#define T_SEQ   4096
#define NB      4
#define NROWS   (NB * T_SEQ)      // 16384
#define SPLIT   8

typedef float f32x4 __attribute__((ext_vector_type(4)));
typedef __bf16 bf16x8 __attribute__((ext_vector_type(8)));
typedef unsigned short u16;

__device__ inline unsigned pk_bf16(float a, float b) {
    unsigned ua = __builtin_bit_cast(unsigned, a);
    unsigned ub = __builtin_bit_cast(unsigned, b);
    ua = (ua + 0x7FFFu + ((ua >> 16) & 1u)) >> 16;   // RNE
    ub = (ub + 0x7FFFu + ((ub >> 16) & 1u)) >> 16;
    return ua | (ub << 16);
}
__device__ inline u16 bf16r(float a) {
    unsigned ua = __builtin_bit_cast(unsigned, a);
    return (u16)((ua + 0x7FFFu + ((ua >> 16) & 1u)) >> 16);
}

// ---------------- W pre-pack: Wpk[kb][n][j] = W_sel[(kb*8+j)*64 + col], bf16 ----------------
__global__ __launch_bounds__(256) void packw_kernel(
    const float* __restrict__ Wq, const float* __restrict__ Wk,
    const float* __restrict__ Wv, unsigned* __restrict__ Wpk)
{
    const int id = blockIdx.x * 256 + threadIdx.x;   // 0..24575
    const int kb = id / 192;
    const int n  = id - kb * 192;
    const int sel = n >> 6, col = n & 63;
    const float* W = sel == 0 ? Wq : (sel == 1 ? Wk : Wv);
    float f[8];
#pragma unroll
    for (int j = 0; j < 8; ++j) f[j] = W[(kb * 8 + j) * 64 + col];
    uint4 o;
    o.x = pk_bf16(f[0], f[1]); o.y = pk_bf16(f[2], f[3]);
    o.z = pk_bf16(f[4], f[5]); o.w = pk_bf16(f[6], f[7]);
    *(uint4*)(Wpk + (size_t)id * 4) = o;
}

// ---------------- QKV projection: streaming LDS-staged GEMM, BK=128 dbuf (R11) --------------
__global__ __launch_bounds__(256) void qkv_kernel(
    const float* __restrict__ x, const unsigned* __restrict__ Wpk,
    u16* __restrict__ Qbf, u16* __restrict__ Kbf, u16* __restrict__ Vt)
{
    __shared__ __align__(16) unsigned Xs[2][32 * 68];   // 32 rows x 128 bf16 (stride 136)
    __shared__ __align__(16) u16 Vbuf[64 * 32];         // V^T bounce: [dim 64][tpos 32]

    const int tid  = threadIdx.x;
    const int w    = tid >> 6;
    const int lane = tid & 63;
    const int nl   = lane & 15;
    const int quad = lane >> 4;
    const long row0 = (long)blockIdx.x * 32;

    const int srow = tid >> 5;          // staging: base row 0..7 (+8 per pass)
    const int scol = (tid & 31) * 4;    // staging col 0..124

    f32x4 acc[2][3] = {};

    float4 nx[4];
#pragma unroll
    for (int p = 0; p < 4; ++p)
        nx[p] = *(const float4*)(x + (row0 + p * 8 + srow) * D_MODEL + scol);

    for (int ch = 0; ch < 8; ++ch) {
        const int buf = ch & 1;
#pragma unroll
        for (int p = 0; p < 4; ++p) {
            uint2 pk2;
            pk2.x = pk_bf16(nx[p].x, nx[p].y);
            pk2.y = pk_bf16(nx[p].z, nx[p].w);
            *(uint2*)&Xs[buf][(p * 8 + srow) * 68 + (scol >> 1)] = pk2;
        }
        __syncthreads();
        if (ch < 7) {
#pragma unroll
            for (int p = 0; p < 4; ++p)
                nx[p] = *(const float4*)(x + (row0 + p * 8 + srow) * D_MODEL
                                           + (ch + 1) * 128 + scol);
        }
#pragma unroll
        for (int kk = 0; kk < 4; ++kk) {
            const bf16x8 a0 = __builtin_bit_cast(bf16x8,
                *(const uint4*)&Xs[buf][nl * 68 + kk * 16 + quad * 4]);
            const bf16x8 a1 = __builtin_bit_cast(bf16x8,
                *(const uint4*)&Xs[buf][(16 + nl) * 68 + kk * 16 + quad * 4]);
            const unsigned* wb = Wpk + (size_t)(ch * 16 + kk * 4 + quad) * 768
                                     + (w * 48 + nl) * 4;
#pragma unroll
            for (int t = 0; t < 3; ++t) {
                const bf16x8 b = __builtin_bit_cast(bf16x8, *(const uint4*)(wb + t * 64));
                acc[0][t] = __builtin_amdgcn_mfma_f32_16x16x32_bf16(a0, b, acc[0][t], 0, 0, 0);
                acc[1][t] = __builtin_amdgcn_mfma_f32_16x16x32_bf16(a1, b, acc[1][t], 0, 0, 0);
            }
        }
        __syncthreads();
    }

    const float QSCALE = 0.04508422f;    // D^-0.5 * log2(e): exp2-domain prescale
#pragma unroll
    for (int t = 0; t < 3; ++t) {
        const int n0c = w * 48 + t * 16;
        const int sel = n0c >> 6;
        const int col = (n0c & 63) + nl;
#pragma unroll
        for (int m = 0; m < 2; ++m) {
            if (sel == 0) {
#pragma unroll
                for (int reg = 0; reg < 4; ++reg)
                    Qbf[(row0 + m * 16 + quad * 4 + reg) * D_HEAD + col] =
                        bf16r(acc[m][t][reg] * QSCALE);
            } else if (sel == 1) {
#pragma unroll
                for (int reg = 0; reg < 4; ++reg)
                    Kbf[(row0 + m * 16 + quad * 4 + reg) * D_HEAD + col] =
                        bf16r(acc[m][t][reg]);
            } else {
                uint2 p2;
                p2.x = pk_bf16(acc[m][t][0], acc[m][t][1]);
                p2.y = pk_bf16(acc[m][t][2], acc[m][t][3]);
                *(uint2*)&Vbuf[col * 32 + m * 16 + quad * 4] = p2;
            }
        }
    }
    __syncthreads();
    {
        const int dim  = tid >> 2;
        const int tseg = (tid & 3) * 8;
        const long bb   = row0 >> 12;
        const int tpos0 = (int)(row0 & 4095);
        const uint4 v = *(const uint4*)&Vbuf[dim * 32 + tseg];
        *(uint4*)&Vt[((bb * 64 + dim) << 12) + tpos0 + tseg] = v;
    }
}

// ---------------- MFMA flash attention: R14 -------------------------------------------------
// R14 theory: R1/R2's WRITE_SIZE (96-105 MB vs 17 MB real output) proved scratch spills —
// load buffers must live in arch VGPRs and the allocator put the VGPR/AGPR boundary at 128,
// spilling ~45 regs per iteration. Fix is structural: phase-split each K-tile so only ONE
// 32-reg load buffer is live at a time:
//   load K -> QK both strips (K dies) -> load V (same slots) -> mask/exp2/pack both strips
//   (V latency hides under softmax VALU) -> PV both strips.
// Peak VGPR-class ~95 (buf32 + S32 + qf16 + addr) -> no spills at any plausible boundary.
// Balanced grid unchanged from R2: tiles (127-p, p) paired = 65 K-tiles/pair, 512 blocks,
// one batch per XCD via gid&3. Po16/Pl layout identical to R10; reduce_kernel unchanged.
__global__ __launch_bounds__(256, 3) void attn_kernel(
    const u16* __restrict__ Qbf, const u16* __restrict__ Kbf,
    const u16* __restrict__ Vt, u16* __restrict__ Po16, float* __restrict__ Pl)
{
    __shared__ __align__(16) u16 Pbuf[4][2][16 * 64];   // 16 KB

    const int tid   = threadIdx.x;
    const int w     = tid >> 6;
    const int lane  = tid & 63;
    const int nl    = lane & 15;
    const int quad  = lane >> 4;
    const int gid   = blockIdx.x;                // 0..511
    const int b     = gid & 3;                   // one batch per XCD pair (gid%8 RR)
    const int idx   = gid >> 2;                  // 0..127
    const int half  = idx & 1;
    const int pair  = idx >> 1;                  // 0..63
    const int sp    = half * 4 + w;              // global split 0..7

    const u16* Kb = Kbf + (size_t)b * T_SEQ * D_HEAD;
    const u16* Vb = Vt  + (size_t)b * D_HEAD * T_SEQ;

    const int tileA = 127 - pair;
    const int tileB = pair;
    const int nA = (tileA * 32 + 95) >> 6;       // 33..64
    const int nB = (tileB * 32 + 95) >> 6;       // nA + nB == 65 for all pairs
    const int cntA = (nA - sp + 7) >> 3;         // sp < 8 <= nA always
    const int ktB0 = sp + 8 * cntA - nA;         // in [0,8)
    const int cntB = (ktB0 < nB) ? ((nB - ktB0 + 7) >> 3) : 0;

// one K-tile: phase-split so only one 32-reg load buffer is live at any point
#define COMPUTEKV(kt_) do {                                                          \
    const int _k0 = (kt_) << 6;                                                      \
    uint4 buf[4][2];                                                                 \
    _Pragma("unroll") for (int t = 0; t < 4; ++t) {                                  \
        const u16* kp = Kb + (size_t)(_k0 + t * 16 + nl) * D_HEAD + quad * 8;        \
        buf[t][0] = *(const uint4*)kp;                                               \
        buf[t][1] = *(const uint4*)(kp + 32);                                        \
    }                                                                                \
    f32x4 S[2][4];                                                                   \
    _Pragma("unroll") for (int m = 0; m < 2; ++m)                                    \
    _Pragma("unroll") for (int t = 0; t < 4; ++t) {                                  \
        f32x4 z = {};                                                                \
        z = __builtin_amdgcn_mfma_f32_16x16x32_bf16(qf[m][0],                        \
                __builtin_bit_cast(bf16x8, buf[t][0]), z, 0, 0, 0);                  \
        S[m][t] = __builtin_amdgcn_mfma_f32_16x16x32_bf16(qf[m][1],                  \
                __builtin_bit_cast(bf16x8, buf[t][1]), z, 0, 0, 0);                  \
    }                                                                                \
    uint4 vbuf[4][2];   /* K buffer dead -> allocator reuses its slots */            \
    _Pragma("unroll") for (int t = 0; t < 4; ++t) {                                  \
        const u16* vp = Vb + (size_t)(t * 16 + nl) * T_SEQ + _k0 + quad * 8;         \
        vbuf[t][0] = *(const uint4*)vp;                                              \
        vbuf[t][1] = *(const uint4*)(vp + 32);                                       \
    }                                                                                \
    _Pragma("unroll") for (int m = 0; m < 2; ++m) {                                  \
        const int _qb = wq0 + m * 16;                                                \
        if (_k0 + 63 > _qb) {                                                        \
            _Pragma("unroll") for (int t = 0; t < 4; ++t)                            \
            _Pragma("unroll") for (int reg = 0; reg < 4; ++reg)                      \
                if (_k0 + t * 16 + nl > _qb + quad * 4 + reg)                        \
                    S[m][t][reg] = -INFINITY;                                        \
        }                                                                            \
        _Pragma("unroll") for (int t = 0; t < 4; ++t)                                \
        _Pragma("unroll") for (int reg = 0; reg < 4; ++reg)                          \
            S[m][t][reg] = exp2f(S[m][t][reg]);                                      \
        _Pragma("unroll") for (int reg = 0; reg < 4; ++reg)                          \
            l[m][reg] += (S[m][0][reg] + S[m][1][reg])                               \
                       + (S[m][2][reg] + S[m][3][reg]);                              \
        u16* pb = Pbuf[w][m];                                                        \
        _Pragma("unroll") for (int t = 0; t < 4; ++t) {                              \
            const int g = 2 * t + (nl >> 3);                                         \
            _Pragma("unroll") for (int reg = 0; reg < 4; ++reg) {                    \
                const int q = quad * 4 + reg;                                        \
                pb[q * 64 + ((g ^ (q & 7)) * 8) + (nl & 7)] = bf16r(S[m][t][reg]);   \
            }                                                                        \
        }                                                                            \
    }                                                                                \
    _Pragma("unroll") for (int m = 0; m < 2; ++m) {                                  \
        const u16* pb = Pbuf[w][m];                                                  \
        const bf16x8 pf0 = __builtin_bit_cast(bf16x8,                                \
            *(const uint4*)&pb[nl * 64 + ((quad ^ (nl & 7)) * 8)]);                  \
        const bf16x8 pf1 = __builtin_bit_cast(bf16x8,                                \
            *(const uint4*)&pb[nl * 64 + (((4 + quad) ^ (nl & 7)) * 8)]);            \
        _Pragma("unroll") for (int t = 0; t < 4; ++t) {                              \
            Ot[m][t] = __builtin_amdgcn_mfma_f32_16x16x32_bf16(pf0,                  \
                        __builtin_bit_cast(bf16x8, vbuf[t][0]), Ot[m][t], 0, 0, 0);  \
            Ot[m][t] = __builtin_amdgcn_mfma_f32_16x16x32_bf16(pf1,                  \
                        __builtin_bit_cast(bf16x8, vbuf[t][1]), Ot[m][t], 0, 0, 0);  \
        }                                                                            \
    }                                                                                \
} while (0)

    auto runTile = [&](const int tile, const int kt0, const int cnt) {
        const int wq0 = tile * 32;

        bf16x8 qf[2][2];
#pragma unroll
        for (int m = 0; m < 2; ++m) {
            const u16* qp = Qbf + ((size_t)b * T_SEQ + wq0 + m * 16 + nl) * D_HEAD + quad * 8;
            qf[m][0] = __builtin_bit_cast(bf16x8, *(const uint4*)qp);
            qf[m][1] = __builtin_bit_cast(bf16x8, *(const uint4*)(qp + 32));
        }

        f32x4 Ot[2][4] = {};
        float l[2][4] = {{0.f,0.f,0.f,0.f},{0.f,0.f,0.f,0.f}};

        int kt = kt0;
        for (int i = 0; i < cnt; ++i, kt += 8)
            COMPUTEKV(kt);

#pragma unroll
        for (int m = 0; m < 2; ++m) {
#pragma unroll
            for (int reg = 0; reg < 4; ++reg) {
                float s = l[m][reg];
                s += __shfl_xor(s, 1);
                s += __shfl_xor(s, 2);
                s += __shfl_xor(s, 4);
                s += __shfl_xor(s, 8);
                l[m][reg] = s;
            }
            const int strip = tile * 2 + m;
            const int bs = b * 256 + strip;
            u16* po = Po16 + ((size_t)sp * 1024 + bs) * 1024;
#pragma unroll
            for (int t = 0; t < 4; ++t) {
                uint2 p2;
                p2.x = pk_bf16(Ot[m][t][0], Ot[m][t][1]);
                p2.y = pk_bf16(Ot[m][t][2], Ot[m][t][3]);
                *(uint2*)&po[(t * 16 + nl) * 16 + quad * 4] = p2;
            }
            if (nl == 0) {
                const size_t gr = (size_t)b * T_SEQ + wq0 + m * 16;
#pragma unroll
                for (int reg = 0; reg < 4; ++reg)
                    Pl[(size_t)sp * NROWS + gr + quad * 4 + reg] = l[m][reg];
            }
        }
    };

    runTile(tileA, sp,   cntA);
    runTile(tileB, ktB0, cntB);

#undef COMPUTEKV
}

// ---------------- merge K-split partials: O[row][col] = sum_sp Po / sum_sp Pl (R10) ---------
__global__ __launch_bounds__(64) void reduce_kernel(
    const u16* __restrict__ Po16, const float* __restrict__ Pl,
    float* __restrict__ O)
{
    __shared__ float linv[16];
    const int bs    = blockIdx.x;
    const int b     = bs >> 8, strip = bs & 255;
    const size_t gr = (size_t)b * T_SEQ + strip * 16;
    const int c     = threadIdx.x;               // col 0..63

    if (c < 16) {
        float s = 0.f;
#pragma unroll
        for (int sp = 0; sp < SPLIT; ++sp) s += Pl[(size_t)sp * NROWS + gr + c];
        linv[c] = 1.0f / s;
    }
    __syncthreads();

    float v[16] = {};
#pragma unroll
    for (int sp = 0; sp < SPLIT; ++sp) {
        const u16* p = Po16 + ((size_t)sp * 1024 + bs) * 1024 + c * 16;
        const uint4 x0 = *(const uint4*)p;
        const uint4 x1 = *(const uint4*)(p + 8);
        const unsigned uu[8] = {x0.x, x0.y, x0.z, x0.w, x1.x, x1.y, x1.z, x1.w};
#pragma unroll
        for (int i = 0; i < 8; ++i) {
            v[2*i]   += __builtin_bit_cast(float, uu[i] << 16);
            v[2*i+1] += __builtin_bit_cast(float, uu[i] & 0xFFFF0000u);
        }
    }
#pragma unroll
    for (int r = 0; r < 16; ++r)
        O[(gr + r) * D_HEAD + c] = v[r] * linv[r];
}

extern "C" void kernel_launch(void* const* d_in, const int* in_sizes, int n_in,
                              void* d_out, int out_size, void* d_ws, size_t ws_size,
                              hipStream_t stream) {
    const float* x  = (const float*)d_in[0];
    const float* Wq = (const float*)d_in[1];
    const float* Wk = (const float*)d_in[2];
    const float* Wv = (const float*)d_in[3];
    float* out = (float*)d_out;

    const size_t rows = NROWS;                        // 16384
    u16* Qbf = (u16*)d_ws;                            // 2 MB
    u16* Kbf = Qbf + rows * D_HEAD;                   // 2 MB
    u16* Vt  = Kbf + rows * D_HEAD;                   // 2 MB (per-batch transposed [b][h][t])
    unsigned* Wpk = (unsigned*)(Vt + rows * D_HEAD);  // 384 KB
    u16* Po16 = (u16*)(Wpk + 128 * 192 * 4);          // SPLIT*16384*64 bf16 = 16 MB
    float* Pl = (float*)(Po16 + (size_t)SPLIT * rows * D_HEAD);  // 512 KB

    hipLaunchKernelGGL(packw_kernel, dim3(96), dim3(256), 0, stream,
                       Wq, Wk, Wv, Wpk);
    hipLaunchKernelGGL(qkv_kernel, dim3(rows / 32), dim3(256), 0, stream,
                       x, Wpk, Qbf, Kbf, Vt);
    hipLaunchKernelGGL(attn_kernel, dim3(512), dim3(256), 0, stream,
                       Qbf, Kbf, Vt, Po16, Pl);
    hipLaunchKernelGGL(reduce_kernel, dim3(NB * 256), dim3(64), 0, stream,
                       Po16, Pl, out);
}